// Round 3
// baseline (190.567 us; speedup 1.0000x reference)
//
#include <hip/hip_runtime.h>
#include <hip/hip_fp16.h>

#define D 128
#define N_NODES 50000
#define EPSP1 1.1f

// ---- bucketed CSR-build parameters ----
#define NPB 128                 // nodes per bucket (dst >> 7)
#define NBUCK 391               // ceil(50000/128)
#define CAP 2560                // staging cap per bucket (mean 2046, std ~45)
#define P1E 1024                // edges per pass-1 block (4 per thread)
#define TS 136                  // LDS tile row stride (bf16 elems)
#define ECAP 1024               // staged epay entries per conv block (mean 256, std 16)

typedef __attribute__((ext_vector_type(8))) short short8;   // 8 bf16 (4 VGPRs)
typedef __attribute__((ext_vector_type(4))) float f32x4;    // MFMA accumulator

__device__ __forceinline__ unsigned short f2bf(float f) {
    unsigned u = __float_as_uint(f);
    u += 0x7FFF + ((u >> 16) & 1);          // round-to-nearest-even
    return (unsigned short)(u >> 16);
}
__device__ __forceinline__ float bf2f(unsigned short h) {
    return __uint_as_float(((unsigned)h) << 16);
}

// ---------------------------------------------------------------------------
// Pass 1 (merged): blocks [0,nb1) do edge bucketing; blocks [nb1,nb1+ncvt)
// do x fp32->bf16; the rest pack the 4 weight matrices to B-fragment order.
// ---------------------------------------------------------------------------
__global__ __launch_bounds__(256) void pass1_all(
    const int* __restrict__ src, const int* __restrict__ dst,
    const float* __restrict__ ew, int* __restrict__ gcnt,
    uint2* __restrict__ gstage, int ne, int nb1,
    const float* __restrict__ x, unsigned short* __restrict__ hb,
    int n4, int ncvt,
    const float* __restrict__ W1a, const float* __restrict__ W1b,
    const float* __restrict__ W2a, const float* __restrict__ W2b,
    unsigned short* __restrict__ wp)
{
    __shared__ int bcnt[NBUCK];
    __shared__ int goff[NBUCK];
    int tid = threadIdx.x;
    int bid = blockIdx.x;

    if (bid < nb1) {
        // ================= edge bucketing (4 edges/thread) =================
        for (int i = tid; i < NBUCK; i += 256) bcnt[i] = 0;
        __syncthreads();
        int e0 = bid * P1E;
        int   rank[4];
        int   buck[4];
        uint2 pay[4];
#pragma unroll
        for (int j = 0; j < 4; ++j) {
            int e = e0 + j * 256 + tid;
            buck[j] = -1;
            if (e < ne) {
                int d_ = dst[e];
                int b  = d_ >> 7;
                int dl = d_ & 127;
                pay[j].x = (unsigned)(src[e] & 0xFFFF) | ((unsigned)dl << 16);
                pay[j].y = (unsigned)__half_as_ushort(__float2half_rn(ew[e]));
                rank[j]  = atomicAdd(&bcnt[b], 1);
                buck[j]  = b;
            }
        }
        __syncthreads();
        for (int i = tid; i < NBUCK; i += 256)
            if (bcnt[i] > 0) goff[i] = atomicAdd(&gcnt[i], bcnt[i]);
        __syncthreads();
#pragma unroll
        for (int j = 0; j < 4; ++j) {
            if (buck[j] >= 0) {
                int pos = goff[buck[j]] + rank[j];
                if (pos < CAP)
                    gstage[(size_t)buck[j] * CAP + pos] = pay[j];
            }
        }
    } else if (bid < nb1 + ncvt) {
        // ================= x fp32 -> bf16 =================
        int base = (bid - nb1) * 2048;     // float4 units
#pragma unroll
        for (int it = 0; it < 8; ++it) {
            int i = base + it * 256 + tid;
            if (i < n4) {
                float4 v = ((const float4*)x)[i];
                ushort4 o;
                o.x = f2bf(v.x); o.y = f2bf(v.y); o.z = f2bf(v.z); o.w = f2bf(v.w);
                ((ushort4*)hb)[i] = o;
            }
        }
    } else {
        // ================= weight pack =================
        int e2 = (bid - nb1 - ncvt) * 256 + tid;  // 0..8191
        if (e2 < 8192) {
            int mat = e2 >> 11;                   // 0..3
            int e   = e2 & 2047;
            const float* W = (mat == 0) ? W1a : (mat == 1) ? W1b : (mat == 2) ? W2a : W2b;
            unsigned short* Wp = wp + (size_t)mat * 16384;
            int col = e & 127;
            int kq  = e >> 7;
            short8 v;
#pragma unroll
            for (int j = 0; j < 8; ++j)
                v[j] = (short)f2bf(W[(size_t)(kq * 8 + j) * 128 + col]);
            ((short8*)Wp)[e] = v;
        }
    }
}

// ---------------------------------------------------------------------------
// CSR build (shuffle-scan version), one block per bucket, 512 threads.
// NPB=128: scan by waves 0-1, base by wave 2.
// ---------------------------------------------------------------------------
__global__ __launch_bounds__(512) void csr_build(
    const uint2* __restrict__ gstage, const int* __restrict__ gcnt,
    unsigned* __restrict__ epay, int* __restrict__ off)
{
    __shared__ int hist[NPB];
    __shared__ int scn[NPB];
    __shared__ int loc[NPB];
    __shared__ int wtot[2];
    __shared__ int base_s;
    __shared__ unsigned csr[CAP];          // 10 KB

    int b = blockIdx.x;
    int t = threadIdx.x;
    int cnt = min(gcnt[b], CAP);

    if (t < NPB) hist[t] = 0;
    __syncthreads();

    uint2 ent[CAP / 512];                  // 5
#pragma unroll
    for (int it = 0; it < CAP / 512; ++it) {
        int i = it * 512 + t;
        if (i < cnt) {
            ent[it] = gstage[(size_t)b * CAP + i];
            atomicAdd(&hist[(ent[it].x >> 16) & 255], 1);
        }
    }
    __syncthreads();

    int w = t >> 6, l = t & 63;
    if (w < 2) {
        // waves 0-1: inclusive shuffle-scan of hist[w*64 .. w*64+63]
        int v = hist[w * 64 + l];
#pragma unroll
        for (int dd = 1; dd < 64; dd <<= 1) {
            int u = __shfl_up(v, dd, 64);
            if (l >= dd) v += u;
        }
        scn[w * 64 + l] = v;
        if (l == 63) wtot[w] = v;
    } else if (w == 2) {
        // wave 2: base = sum of preceding bucket counts
        int v = 0;
        for (int i = l; i < NBUCK; i += 64)
            if (i < b) v += min(gcnt[i], CAP);
#pragma unroll
        for (int dd = 32; dd > 0; dd >>= 1) v += __shfl_down(v, dd, 64);
        if (l == 0) base_s = v;
    }
    __syncthreads();

    if (t < NPB) {
        int pre = (t >= 64) ? wtot[0] : 0;
        int incl = scn[t] + pre;
        int excl = incl - hist[t];
        int node = (b << 7) + t;
        if (node <= N_NODES) off[node] = base_s + excl;
        loc[t] = excl;
    }
    __syncthreads();

#pragma unroll
    for (int it = 0; it < CAP / 512; ++it) {
        int i = it * 512 + t;
        if (i < cnt) {
            int dl = (ent[it].x >> 16) & 255;
            int p = atomicAdd(&loc[dl], 1);
            csr[p] = (ent[it].x & 0xFFFF) | (ent[it].y << 16);
        }
    }
    __syncthreads();

    for (int i = t; i < cnt; i += 512)
        epay[base_s + i] = csr[i];
}

// ---------------------------------------------------------------------------
// Per-quarter gather body.  L=true: payload words from LDS stage; L=false:
// from global (overflow fallback, statistically never taken).
// __forceinline__ so clang's infer-address-space turns eLp loads into ds_read.
// ---------------------------------------------------------------------------
template<bool L>
__device__ __forceinline__ void gather_node(
    const unsigned short* __restrict__ h,
    const unsigned* eLp, const unsigned* __restrict__ egp,
    int lb, int le, int sub, float* acc)
{
    int i = lb;
    for (; i + 4 <= le; i += 4) {          // 4 rows in flight per quarter
        unsigned p0 = L ? eLp[i]     : egp[i];
        unsigned p1 = L ? eLp[i + 1] : egp[i + 1];
        unsigned p2 = L ? eLp[i + 2] : egp[i + 2];
        unsigned p3 = L ? eLp[i + 3] : egp[i + 3];
        short8 v0 = ((const short8*)(h + (size_t)(p0 & 0xFFFF) * D))[sub];
        short8 v1 = ((const short8*)(h + (size_t)(p1 & 0xFFFF) * D))[sub];
        short8 v2 = ((const short8*)(h + (size_t)(p2 & 0xFFFF) * D))[sub];
        short8 v3 = ((const short8*)(h + (size_t)(p3 & 0xFFFF) * D))[sub];
        float w0 = __half2float(__ushort_as_half((unsigned short)(p0 >> 16)));
        float w1 = __half2float(__ushort_as_half((unsigned short)(p1 >> 16)));
        float w2 = __half2float(__ushort_as_half((unsigned short)(p2 >> 16)));
        float w3 = __half2float(__ushort_as_half((unsigned short)(p3 >> 16)));
#pragma unroll
        for (int c = 0; c < 8; ++c)
            acc[c] += w0 * bf2f((unsigned short)v0[c]) + w1 * bf2f((unsigned short)v1[c])
                    + w2 * bf2f((unsigned short)v2[c]) + w3 * bf2f((unsigned short)v3[c]);
    }
    for (; i < le; ++i) {                  // <=3 tail edges
        unsigned p0 = L ? eLp[i] : egp[i];
        short8 v0 = ((const short8*)(h + (size_t)(p0 & 0xFFFF) * D))[sub];
        float w0 = __half2float(__ushort_as_half((unsigned short)(p0 >> 16)));
#pragma unroll
        for (int c = 0; c < 8; ++c)
            acc[c] += w0 * bf2f((unsigned short)v0[c]);
    }
}

// ---------------------------------------------------------------------------
// Fused GIN conv:
//   block = 16 nodes, 256 threads = 4 waves; each 16-lane QUARTER owns one
//   node (4 parallel edge-chains per wave, no cross-quarter shuffle combine).
//   Block's CSR payload range is contiguous -> coalesced stage into LDS,
//   breaking the epay->h load dependency chain.
//   MLP: shared 16-row tile; each wave computes 2 of 8 column-groups.
// ---------------------------------------------------------------------------
template<int RELU2, int OUT_F32>
__global__ __launch_bounds__(256, 8) void conv_fused(
    const unsigned short* __restrict__ h, const int* __restrict__ off,
    const unsigned* __restrict__ epay,
    const unsigned short* __restrict__ WpA,
    const unsigned short* __restrict__ WpB,
    void* __restrict__ outv, int n)
{
    __shared__ unsigned short t1[16 * TS];   // 4.25 KB  z tile
    __shared__ unsigned short t2[16 * TS];   // 4.25 KB  relu(GEMM1) tile
    __shared__ unsigned eL[ECAP];            // 4 KB     staged edge payloads
    __shared__ int offs[17];

    int tid  = threadIdx.x;
    int wave = tid >> 6;
    int lane = tid & 63;
    int qtr  = lane >> 4;       // 0..3 (== MFMA quad)
    int sub  = lane & 15;       // (== MFMA lc)
    int nb   = blockIdx.x * 16;

    // ---- stage off[] and the block's contiguous epay range
    if (tid < 17) offs[tid] = off[min(nb + tid, n)];
    __syncthreads();
    int ebeg = offs[0];
    int ecnt = offs[16] - ebeg;
    int stg  = min(ecnt, ECAP);
    for (int i = tid; i < stg; i += 256) eL[i] = epay[ebeg + i];
    __syncthreads();

    // ================= gather: one node per quarter =================
    int row  = wave * 4 + qtr;
    int node = nb + row;
    int lb = offs[row]     - ebeg;
    int le = offs[row + 1] - ebeg;

    float acc[8];
#pragma unroll
    for (int c = 0; c < 8; ++c) acc[c] = 0.f;

    if (ecnt <= ECAP)
        gather_node<true >(h, eL, epay + ebeg, lb, le, sub, acc);
    else
        gather_node<false>(h, eL, epay + ebeg, lb, le, sub, acc);

    // GIN update + store z row (each quarter owns a distinct row)
    {
        const short8 zero8 = {0, 0, 0, 0, 0, 0, 0, 0};
        short8 o;
        if (node < n) {
            short8 xv = ((const short8*)(h + (size_t)node * D))[sub];
#pragma unroll
            for (int c = 0; c < 8; ++c)
                o[c] = (short)f2bf(acc[c] + EPSP1 * bf2f((unsigned short)xv[c]));
        } else {
            o = zero8;
        }
        *(short8*)&t1[row * TS + sub * 8] = o;
    }
    __syncthreads();

    // ================= GEMM1: z @ WpA, relu -> t2 =================
    short8 a[4];
#pragma unroll
    for (int kk = 0; kk < 4; ++kk)
        a[kk] = *(const short8*)&t1[sub * TS + kk * 32 + qtr * 8];

    f32x4 acc2[2];
#pragma unroll
    for (int j = 0; j < 2; ++j) acc2[j] = (f32x4){0.f, 0.f, 0.f, 0.f};

#pragma unroll
    for (int j = 0; j < 2; ++j) {
        int cf = wave * 2 + j;
        short8 b[4];
#pragma unroll
        for (int kk = 0; kk < 4; ++kk)
            b[kk] = *(const short8*)(WpA + ((size_t)(kk * 4 + qtr) * 128 + cf * 16 + sub) * 8);
#pragma unroll
        for (int kk = 0; kk < 4; ++kk)
            acc2[j] = __builtin_amdgcn_mfma_f32_16x16x32_bf16(a[kk], b[kk], acc2[j], 0, 0, 0);
    }

#pragma unroll
    for (int j = 0; j < 2; ++j) {
        int cf = wave * 2 + j;
#pragma unroll
        for (int reg = 0; reg < 4; ++reg) {
            int r = qtr * 4 + reg;
            t2[r * TS + cf * 16 + sub] = f2bf(fmaxf(acc2[j][reg], 0.f));
        }
    }
    __syncthreads();

    // ================= GEMM2: relu(.) @ WpB =================
#pragma unroll
    for (int kk = 0; kk < 4; ++kk)
        a[kk] = *(const short8*)&t2[sub * TS + kk * 32 + qtr * 8];

#pragma unroll
    for (int j = 0; j < 2; ++j) acc2[j] = (f32x4){0.f, 0.f, 0.f, 0.f};

#pragma unroll
    for (int j = 0; j < 2; ++j) {
        int cf = wave * 2 + j;
        short8 b[4];
#pragma unroll
        for (int kk = 0; kk < 4; ++kk)
            b[kk] = *(const short8*)(WpB + ((size_t)(kk * 4 + qtr) * 128 + cf * 16 + sub) * 8);
#pragma unroll
        for (int kk = 0; kk < 4; ++kk)
            acc2[j] = __builtin_amdgcn_mfma_f32_16x16x32_bf16(a[kk], b[kk], acc2[j], 0, 0, 0);
    }

#pragma unroll
    for (int j = 0; j < 2; ++j) {
        int cf = wave * 2 + j;
#pragma unroll
        for (int reg = 0; reg < 4; ++reg) {
            int r = nb + qtr * 4 + reg;
            if (r < n) {
                float v = acc2[j][reg];
                if (RELU2) v = fmaxf(v, 0.f);
                int col = cf * 16 + sub;
                if (OUT_F32)
                    ((float*)outv)[(size_t)r * D + col] = v;
                else
                    ((unsigned short*)outv)[(size_t)r * D + col] = f2bf(v);
            }
        }
    }
}

extern "C" void kernel_launch(void* const* d_in, const int* in_sizes, int n_in,
                              void* d_out, int out_size, void* d_ws, size_t ws_size,
                              hipStream_t stream) {
    const float* x   = (const float*)d_in[0];
    const int*   ei  = (const int*)d_in[1];
    const float* ew  = (const float*)d_in[2];
    const float* W1a = (const float*)d_in[3];
    const float* W1b = (const float*)d_in[4];
    const float* W2a = (const float*)d_in[5];
    const float* W2b = (const float*)d_in[6];
    float* out = (float*)d_out;

    int n_edges = in_sizes[2];                 // 800000
    const int* src = ei;
    const int* dst = ei + n_edges;

    size_t node_elems = (size_t)N_NODES * D;   // 6.4M
    unsigned short* hb = (unsigned short*)d_ws;        // 12.8 MB  bf16 node features
    unsigned short* zb = hb + node_elems;              // 12.8 MB  conv1 output (bf16)
    unsigned short* wp = zb + node_elems;              // 4 x 32 KB packed weights
    unsigned* epay = (unsigned*)(wp + 4 * 16384);      // E x 4B final CSR payload
    uint2*  gstage = (uint2*)(epay + n_edges);         // NBUCK x CAP x 8B staging
    int*    gcnt   = (int*)(gstage + (size_t)NBUCK * CAP);  // NBUCK
    int*    off    = gcnt + NBUCK;                     // N+1

    int nb1   = (n_edges + P1E - 1) / P1E;              // 782
    int n4    = (int)(node_elems / 4);                  // 1.6M float4
    int ncvt  = (n4 + 2047) / 2048;                     // 782
    int npack = 32;                                     // 8192 short8 / 256
    int cgrid = (N_NODES + 15) / 16;                    // 3125

    hipMemsetAsync(gcnt, 0, NBUCK * sizeof(int), stream);

    // ---- pass 1 (merged): bucket | x->bf16 | weight pack
    pass1_all<<<nb1 + ncvt + npack, 256, 0, stream>>>(
        src, dst, ew, gcnt, gstage, n_edges, nb1,
        x, hb, n4, ncvt, W1a, W1b, W2a, W2b, wp);

    // ---- CSR build
    csr_build<<<NBUCK, 512, 0, stream>>>(gstage, gcnt, epay, off);

    unsigned short* wp0 = wp;
    unsigned short* wp1 = wp + 16384;
    unsigned short* wp2 = wp + 2 * 16384;
    unsigned short* wp3 = wp + 3 * 16384;

    // ---- conv 1 (fused gather + GIN update + MLP, inter-conv relu fused)
    conv_fused<1, 0><<<cgrid, 256, 0, stream>>>(hb, off, epay, wp0, wp1, zb, N_NODES);

    // ---- conv 2 (fp32 out, no final relu)
    conv_fused<0, 1><<<cgrid, 256, 0, stream>>>(zb, off, epay, wp2, wp3, out, N_NODES);
}

// Round 4
// 177.907 us; speedup vs baseline: 1.0712x; 1.0712x over previous
//
#include <hip/hip_runtime.h>
#include <hip/hip_fp16.h>

#define D 128
#define N_NODES 50000
#define EPSP1 1.1f

// ---- bucketed CSR-build parameters ----
#define NPB 128                 // nodes per bucket (dst >> 7)
#define NBUCK 391               // ceil(50000/128)
#define CAP 2560                // staging cap per bucket (mean 2046, std ~45)
#define P1E 4096                // edges per pass-1 block (8 per thread, 512 thr)
#define TS 136                  // LDS tile row stride (bf16 elems)

typedef __attribute__((ext_vector_type(8))) short short8;   // 8 bf16 (4 VGPRs)
typedef __attribute__((ext_vector_type(4))) float f32x4;    // MFMA accumulator

__device__ __forceinline__ unsigned short f2bf(float f) {
    unsigned u = __float_as_uint(f);
    u += 0x7FFF + ((u >> 16) & 1);          // round-to-nearest-even
    return (unsigned short)(u >> 16);
}
__device__ __forceinline__ float bf2f(unsigned short h) {
    return __uint_as_float(((unsigned)h) << 16);
}

// ---------------------------------------------------------------------------
// Pass 1 (merged, 512 thr): blocks [0,nb1) edge bucketing (8 edges/thread,
// ~10.5 edges per bucket per block -> ~84B contiguous store chunks, no
// sector write amplification); [nb1,nb1+ncvt) x fp32->bf16; rest weight pack.
// ---------------------------------------------------------------------------
__global__ __launch_bounds__(512, 4) void pass1_all(
    const int* __restrict__ src, const int* __restrict__ dst,
    const float* __restrict__ ew, int* __restrict__ gcnt,
    uint2* __restrict__ gstage, int ne, int nb1,
    const float* __restrict__ x, unsigned short* __restrict__ hb,
    int n4, int ncvt,
    const float* __restrict__ W1a, const float* __restrict__ W1b,
    const float* __restrict__ W2a, const float* __restrict__ W2b,
    unsigned short* __restrict__ wp)
{
    __shared__ int bcnt[NBUCK];
    __shared__ int goff[NBUCK];
    int tid = threadIdx.x;
    int bid = blockIdx.x;

    if (bid < nb1) {
        // ================= edge bucketing (8 edges/thread) =================
        for (int i = tid; i < NBUCK; i += 512) bcnt[i] = 0;
        __syncthreads();
        int e0 = bid * P1E;
        int   rank[8];
        int   buck[8];
        uint2 pay[8];
#pragma unroll
        for (int j = 0; j < 8; ++j) {
            int e = e0 + j * 512 + tid;
            buck[j] = -1;
            if (e < ne) {
                int d_ = dst[e];
                int b  = d_ >> 7;
                int dl = d_ & 127;
                pay[j].x = (unsigned)(src[e] & 0xFFFF) | ((unsigned)dl << 16);
                pay[j].y = (unsigned)__half_as_ushort(__float2half_rn(ew[e]));
                rank[j]  = atomicAdd(&bcnt[b], 1);
                buck[j]  = b;
            }
        }
        __syncthreads();
        for (int i = tid; i < NBUCK; i += 512)
            if (bcnt[i] > 0) goff[i] = atomicAdd(&gcnt[i], bcnt[i]);
        __syncthreads();
#pragma unroll
        for (int j = 0; j < 8; ++j) {
            if (buck[j] >= 0) {
                int pos = goff[buck[j]] + rank[j];
                if (pos < CAP)
                    gstage[(size_t)buck[j] * CAP + pos] = pay[j];
            }
        }
    } else if (bid < nb1 + ncvt) {
        // ================= x fp32 -> bf16 =================
        int base = (bid - nb1) * 4096;     // float4 units
#pragma unroll
        for (int it = 0; it < 8; ++it) {
            int i = base + it * 512 + tid;
            if (i < n4) {
                float4 v = ((const float4*)x)[i];
                ushort4 o;
                o.x = f2bf(v.x); o.y = f2bf(v.y); o.z = f2bf(v.z); o.w = f2bf(v.w);
                ((ushort4*)hb)[i] = o;
            }
        }
    } else {
        // ================= weight pack =================
        int e2 = (bid - nb1 - ncvt) * 512 + tid;  // 0..8191
        if (e2 < 8192) {
            int mat = e2 >> 11;                   // 0..3
            int e   = e2 & 2047;
            const float* W = (mat == 0) ? W1a : (mat == 1) ? W1b : (mat == 2) ? W2a : W2b;
            unsigned short* Wp = wp + (size_t)mat * 16384;
            int col = e & 127;
            int kq  = e >> 7;
            short8 v;
#pragma unroll
            for (int j = 0; j < 8; ++j)
                v[j] = (short)f2bf(W[(size_t)(kq * 8 + j) * 128 + col]);
            ((short8*)Wp)[e] = v;
        }
    }
}

// ---------------------------------------------------------------------------
// CSR build (shuffle-scan version), one block per bucket, 512 threads.
// NPB=128: scan by waves 0-1, base by wave 2.
// ---------------------------------------------------------------------------
__global__ __launch_bounds__(512) void csr_build(
    const uint2* __restrict__ gstage, const int* __restrict__ gcnt,
    unsigned* __restrict__ epay, int* __restrict__ off)
{
    __shared__ int hist[NPB];
    __shared__ int scn[NPB];
    __shared__ int loc[NPB];
    __shared__ int wtot[2];
    __shared__ int base_s;
    __shared__ unsigned csr[CAP];          // 10 KB

    int b = blockIdx.x;
    int t = threadIdx.x;
    int cnt = min(gcnt[b], CAP);

    if (t < NPB) hist[t] = 0;
    __syncthreads();

    uint2 ent[CAP / 512];                  // 5
#pragma unroll
    for (int it = 0; it < CAP / 512; ++it) {
        int i = it * 512 + t;
        if (i < cnt) {
            ent[it] = gstage[(size_t)b * CAP + i];
            atomicAdd(&hist[(ent[it].x >> 16) & 255], 1);
        }
    }
    __syncthreads();

    int w = t >> 6, l = t & 63;
    if (w < 2) {
        // waves 0-1: inclusive shuffle-scan of hist[w*64 .. w*64+63]
        int v = hist[w * 64 + l];
#pragma unroll
        for (int dd = 1; dd < 64; dd <<= 1) {
            int u = __shfl_up(v, dd, 64);
            if (l >= dd) v += u;
        }
        scn[w * 64 + l] = v;
        if (l == 63) wtot[w] = v;
    } else if (w == 2) {
        // wave 2: base = sum of preceding bucket counts
        int v = 0;
        for (int i = l; i < NBUCK; i += 64)
            if (i < b) v += min(gcnt[i], CAP);
#pragma unroll
        for (int dd = 32; dd > 0; dd >>= 1) v += __shfl_down(v, dd, 64);
        if (l == 0) base_s = v;
    }
    __syncthreads();

    if (t < NPB) {
        int pre = (t >= 64) ? wtot[0] : 0;
        int incl = scn[t] + pre;
        int excl = incl - hist[t];
        int node = (b << 7) + t;
        if (node <= N_NODES) off[node] = base_s + excl;
        loc[t] = excl;
    }
    __syncthreads();

#pragma unroll
    for (int it = 0; it < CAP / 512; ++it) {
        int i = it * 512 + t;
        if (i < cnt) {
            int dl = (ent[it].x >> 16) & 255;
            int p = atomicAdd(&loc[dl], 1);
            csr[p] = (ent[it].x & 0xFFFF) | (ent[it].y << 16);
        }
    }
    __syncthreads();

    for (int i = t; i < cnt; i += 512)
        epay[base_s + i] = csr[i];
}

// ---------------------------------------------------------------------------
// Fused GIN conv:
//   block = 32 nodes, 512 threads = 8 waves; each 16-lane QUARTER owns one
//   node (same gather parallelism as before, half the blocks -> half the
//   per-conv weight traffic: 1563 x 64 KB = 100 MB L2).
//   MLP: shared 32-row tile; each wave computes exactly ONE of the 8
//   column-groups (a-frags loaded per-kk -> low VGPR).  2 barriers.
// ---------------------------------------------------------------------------
template<int RELU2, int OUT_F32>
__global__ __launch_bounds__(512, 8) void conv_fused(
    const unsigned short* __restrict__ h, const int* __restrict__ off,
    const unsigned* __restrict__ epay,
    const unsigned short* __restrict__ WpA,
    const unsigned short* __restrict__ WpB,
    void* __restrict__ outv, int n)
{
    __shared__ unsigned short t1[32 * TS];   // 8.5 KB  z tile
    __shared__ unsigned short t2[32 * TS];   // 8.5 KB  relu(GEMM1) tile
    __shared__ int offs[33];

    int tid  = threadIdx.x;
    int wave = tid >> 6;
    int lane = tid & 63;
    int qtr  = lane >> 4;       // 0..3 (== MFMA quad)
    int sub  = lane & 15;       // (== MFMA lc)
    int nb   = blockIdx.x * 32;

    if (tid < 33) offs[tid] = off[min(nb + tid, n)];
    __syncthreads();

    // ================= gather: one node per quarter =================
    int row  = wave * 4 + qtr;  // 0..31
    int node = nb + row;
    int beg = offs[row];
    int end = offs[row + 1];

    float acc[8];
#pragma unroll
    for (int c = 0; c < 8; ++c) acc[c] = 0.f;

    int i = beg;
    for (; i + 4 <= end; i += 4) {          // 4 rows in flight per quarter
        unsigned p0 = epay[i];
        unsigned p1 = epay[i + 1];
        unsigned p2 = epay[i + 2];
        unsigned p3 = epay[i + 3];
        short8 v0 = ((const short8*)(h + (size_t)(p0 & 0xFFFF) * D))[sub];
        short8 v1 = ((const short8*)(h + (size_t)(p1 & 0xFFFF) * D))[sub];
        short8 v2 = ((const short8*)(h + (size_t)(p2 & 0xFFFF) * D))[sub];
        short8 v3 = ((const short8*)(h + (size_t)(p3 & 0xFFFF) * D))[sub];
        float w0 = __half2float(__ushort_as_half((unsigned short)(p0 >> 16)));
        float w1 = __half2float(__ushort_as_half((unsigned short)(p1 >> 16)));
        float w2 = __half2float(__ushort_as_half((unsigned short)(p2 >> 16)));
        float w3 = __half2float(__ushort_as_half((unsigned short)(p3 >> 16)));
#pragma unroll
        for (int c = 0; c < 8; ++c)
            acc[c] += w0 * bf2f((unsigned short)v0[c]) + w1 * bf2f((unsigned short)v1[c])
                    + w2 * bf2f((unsigned short)v2[c]) + w3 * bf2f((unsigned short)v3[c]);
    }
    for (; i < end; ++i) {                  // <=3 tail edges
        unsigned p0 = epay[i];
        short8 v0 = ((const short8*)(h + (size_t)(p0 & 0xFFFF) * D))[sub];
        float w0 = __half2float(__ushort_as_half((unsigned short)(p0 >> 16)));
#pragma unroll
        for (int c = 0; c < 8; ++c)
            acc[c] += w0 * bf2f((unsigned short)v0[c]);
    }

    // GIN update + store z row (each quarter owns a distinct row)
    {
        const short8 zero8 = {0, 0, 0, 0, 0, 0, 0, 0};
        short8 o;
        if (node < n) {
            short8 xv = ((const short8*)(h + (size_t)node * D))[sub];
#pragma unroll
            for (int c = 0; c < 8; ++c)
                o[c] = (short)f2bf(acc[c] + EPSP1 * bf2f((unsigned short)xv[c]));
        } else {
            o = zero8;
        }
        *(short8*)&t1[row * TS + sub * 8] = o;
    }
    __syncthreads();

    // ================= GEMM1: z @ WpA, relu -> t2 =================
    int cf = wave;              // this wave's column-group
    f32x4 acc2[2];
    acc2[0] = (f32x4){0.f, 0.f, 0.f, 0.f};
    acc2[1] = (f32x4){0.f, 0.f, 0.f, 0.f};

#pragma unroll
    for (int kk = 0; kk < 4; ++kk) {
        short8 a0 = *(const short8*)&t1[(sub)      * TS + kk * 32 + qtr * 8];
        short8 a1 = *(const short8*)&t1[(16 + sub) * TS + kk * 32 + qtr * 8];
        short8 b  = *(const short8*)(WpA + ((size_t)(kk * 4 + qtr) * 128 + cf * 16 + sub) * 8);
        acc2[0] = __builtin_amdgcn_mfma_f32_16x16x32_bf16(a0, b, acc2[0], 0, 0, 0);
        acc2[1] = __builtin_amdgcn_mfma_f32_16x16x32_bf16(a1, b, acc2[1], 0, 0, 0);
    }

#pragma unroll
    for (int s = 0; s < 2; ++s)
#pragma unroll
        for (int reg = 0; reg < 4; ++reg) {
            int r = s * 16 + qtr * 4 + reg;
            t2[r * TS + cf * 16 + sub] = f2bf(fmaxf(acc2[s][reg], 0.f));
        }
    __syncthreads();

    // ================= GEMM2: relu(.) @ WpB =================
    acc2[0] = (f32x4){0.f, 0.f, 0.f, 0.f};
    acc2[1] = (f32x4){0.f, 0.f, 0.f, 0.f};

#pragma unroll
    for (int kk = 0; kk < 4; ++kk) {
        short8 a0 = *(const short8*)&t2[(sub)      * TS + kk * 32 + qtr * 8];
        short8 a1 = *(const short8*)&t2[(16 + sub) * TS + kk * 32 + qtr * 8];
        short8 b  = *(const short8*)(WpB + ((size_t)(kk * 4 + qtr) * 128 + cf * 16 + sub) * 8);
        acc2[0] = __builtin_amdgcn_mfma_f32_16x16x32_bf16(a0, b, acc2[0], 0, 0, 0);
        acc2[1] = __builtin_amdgcn_mfma_f32_16x16x32_bf16(a1, b, acc2[1], 0, 0, 0);
    }

#pragma unroll
    for (int s = 0; s < 2; ++s)
#pragma unroll
        for (int reg = 0; reg < 4; ++reg) {
            int r = nb + s * 16 + qtr * 4 + reg;
            if (r < n) {
                float v = acc2[s][reg];
                if (RELU2) v = fmaxf(v, 0.f);
                int col = cf * 16 + sub;
                if (OUT_F32)
                    ((float*)outv)[(size_t)r * D + col] = v;
                else
                    ((unsigned short*)outv)[(size_t)r * D + col] = f2bf(v);
            }
        }
}

extern "C" void kernel_launch(void* const* d_in, const int* in_sizes, int n_in,
                              void* d_out, int out_size, void* d_ws, size_t ws_size,
                              hipStream_t stream) {
    const float* x   = (const float*)d_in[0];
    const int*   ei  = (const int*)d_in[1];
    const float* ew  = (const float*)d_in[2];
    const float* W1a = (const float*)d_in[3];
    const float* W1b = (const float*)d_in[4];
    const float* W2a = (const float*)d_in[5];
    const float* W2b = (const float*)d_in[6];
    float* out = (float*)d_out;

    int n_edges = in_sizes[2];                 // 800000
    const int* src = ei;
    const int* dst = ei + n_edges;

    size_t node_elems = (size_t)N_NODES * D;   // 6.4M
    unsigned short* hb = (unsigned short*)d_ws;        // 12.8 MB  bf16 node features
    unsigned short* zb = hb + node_elems;              // 12.8 MB  conv1 output (bf16)
    unsigned short* wp = zb + node_elems;              // 4 x 32 KB packed weights
    unsigned* epay = (unsigned*)(wp + 4 * 16384);      // E x 4B final CSR payload
    uint2*  gstage = (uint2*)(epay + n_edges);         // NBUCK x CAP x 8B staging
    int*    gcnt   = (int*)(gstage + (size_t)NBUCK * CAP);  // NBUCK
    int*    off    = gcnt + NBUCK;                     // N+1

    int nb1   = (n_edges + P1E - 1) / P1E;              // 196
    int n4    = (int)(node_elems / 4);                  // 1.6M float4
    int ncvt  = (n4 + 4095) / 4096;                     // 391
    int npack = 16;                                     // 8192 short8 / 512
    int cgrid = (N_NODES + 31) / 32;                    // 1563

    hipMemsetAsync(gcnt, 0, NBUCK * sizeof(int), stream);

    // ---- pass 1 (merged): bucket | x->bf16 | weight pack
    pass1_all<<<nb1 + ncvt + npack, 512, 0, stream>>>(
        src, dst, ew, gcnt, gstage, n_edges, nb1,
        x, hb, n4, ncvt, W1a, W1b, W2a, W2b, wp);

    // ---- CSR build
    csr_build<<<NBUCK, 512, 0, stream>>>(gstage, gcnt, epay, off);

    unsigned short* wp0 = wp;
    unsigned short* wp1 = wp + 16384;
    unsigned short* wp2 = wp + 2 * 16384;
    unsigned short* wp3 = wp + 3 * 16384;

    // ---- conv 1 (fused gather + GIN update + MLP, inter-conv relu fused)
    conv_fused<1, 0><<<cgrid, 512, 0, stream>>>(hb, off, epay, wp0, wp1, zb, N_NODES);

    // ---- conv 2 (fp32 out, no final relu)
    conv_fused<0, 1><<<cgrid, 512, 0, stream>>>(zb, off, epay, wp2, wp3, out, N_NODES);
}